// Round 4
// baseline (69.704 us; speedup 1.0000x reference)
//
#include <hip/hip_runtime.h>

// Embedding gather: out[row, :] = table[idx[row], :]
//   rows   = BATCH*SLOTS*NNZ = 4096*26*8 = 851,968
//   EMB    = 64 floats = 256 B per row = 16 float4 "units"
//   TOTAL units = 13,631,488
//
// R2: nontemporal stores (67.6 us, +18% over cached stores) — keeps the
//     218 MB write stream from evicting the ~L3-resident table.
// R3: persistent grid-stride with unrolled independent iterations.
//     Old: 53K short-lived blocks, 1 dependent load->store per thread
//     (MLP=1 per thread against ~900cy random-gather latency).
//     New: 4096 blocks x 256 thr, 13 units/thread, #pragma unroll lets
//     the compiler issue multiple global_load_dwordx4 before the nt
//     stores -> more gathers in flight per wave.

#define NROWS   (4096 * 26 * 8)
#define F4_PER_ROW 16
#define TOTAL   ((size_t)NROWS * F4_PER_ROW)   // 13,631,488
#define BLOCKS  4096
#define TPB     256

typedef float vfloat4 __attribute__((ext_vector_type(4)));

__global__ __launch_bounds__(TPB)
void All2AllDenseEmbedding_76828374991711_kernel(const int* __restrict__ idx,
                                                 const vfloat4* __restrict__ table,
                                                 vfloat4* __restrict__ out) {
    const unsigned nthreads = BLOCKS * TPB;                 // 1,048,576
    unsigned gid = blockIdx.x * TPB + threadIdx.x;

    // TOTAL / nthreads = 13 exactly; unroll so loads get hoisted together.
    #pragma unroll
    for (int i = 0; i < 13; ++i) {
        size_t u   = (size_t)gid + (size_t)i * nthreads;    // float4 unit
        unsigned row = (unsigned)(u >> 4);
        unsigned col = (unsigned)(u & 15u);
        size_t r = (size_t)(unsigned)idx[row];
        vfloat4 v = table[r * F4_PER_ROW + col];
        __builtin_nontemporal_store(v, &out[u]);
    }
}

extern "C" void kernel_launch(void* const* d_in, const int* in_sizes, int n_in,
                              void* d_out, int out_size, void* d_ws, size_t ws_size,
                              hipStream_t stream) {
    const int*     idx   = (const int*)d_in[0];      // inputs [B,S,N] int32
    const vfloat4* table = (const vfloat4*)d_in[1];  // table  [VOCAB, 64] f32
    vfloat4*       out   = (vfloat4*)d_out;          // [B,S,N,64] f32

    All2AllDenseEmbedding_76828374991711_kernel<<<BLOCKS, TPB, 0, stream>>>(idx, table, out);
}

// Round 5
// 66.711 us; speedup vs baseline: 1.0449x; 1.0449x over previous
//
#include <hip/hip_runtime.h>

// Embedding gather: out[row, :] = table[idx[row], :]
//   rows   = BATCH*SLOTS*NNZ = 4096*26*8 = 851,968
//   EMB    = 64 floats = 256 B per row = 16 float4
// Layout: 16 lanes per row, each lane moves one float4 (16 B).
// Block 256 threads handles 16 rows.
//
// R2 (WINNER, 67.6 us): nontemporal output stores via clang native vector
// type — keeps the 218 MB write stream from evicting the ~L3-resident
// table, so duplicate index rows stay L3 hits.
// R3 (REVERTED, 69.7 us): grid-stride MLP=13 regressed ~3% — gather is
// bandwidth-bound, not latency-bound; extra in-flight state bought nothing.

#define NROWS (4096 * 26 * 8)
#define F4_PER_ROW 16   // 64 floats / 4

typedef float vfloat4 __attribute__((ext_vector_type(4)));

__global__ __launch_bounds__(256)
void All2AllDenseEmbedding_76828374991711_kernel(const int* __restrict__ idx,
                                                 const vfloat4* __restrict__ table,
                                                 vfloat4* __restrict__ out) {
    unsigned gid = blockIdx.x * 256u + threadIdx.x;
    unsigned row = gid >> 4;      // which output row
    unsigned col = gid & 15u;     // which float4 within the row
    if (row < NROWS) {
        size_t r = (size_t)(unsigned)idx[row];           // table row (0 .. 1M-1)
        vfloat4 v = table[r * F4_PER_ROW + col];         // cached read (want L3 hits)
        __builtin_nontemporal_store(v, &out[(size_t)row * F4_PER_ROW + col]);
    }
}

extern "C" void kernel_launch(void* const* d_in, const int* in_sizes, int n_in,
                              void* d_out, int out_size, void* d_ws, size_t ws_size,
                              hipStream_t stream) {
    const int*     idx   = (const int*)d_in[0];      // inputs [B,S,N] int32
    const vfloat4* table = (const vfloat4*)d_in[1];  // table  [VOCAB, 64] f32
    vfloat4*       out   = (vfloat4*)d_out;          // [B,S,N,64] f32

    unsigned total_threads = NROWS * F4_PER_ROW;     // one thread per float4
    unsigned grid = (total_threads + 255) / 256;
    All2AllDenseEmbedding_76828374991711_kernel<<<grid, 256, 0, stream>>>(idx, table, out);
}